// Round 2
// baseline (148.493 us; speedup 1.0000x reference)
//
#include <hip/hip_runtime.h>

#define N_ 256
#define C_ 2048
#define HW_ 49
#define CPB 64
#define NCC (C_/CPB)   // 32

typedef unsigned int u32;

// local-channel base in sx: 70 channels (3 halo low, 64 main, 3 halo high).
// Main chunk starts at 148 (16B-aligned for float4 reads); halo-low at 0, gap at 147.
#define CHB(lc) ((lc) * HW_ + ((lc) >= 3 ? 1 : 0))

// ---------------- kernel 1: per-chunk channel-pool partials ----------------
__global__ __launch_bounds__(256) void k_poolc(const float* __restrict__ x,
                                               float* __restrict__ psum,
                                               float* __restrict__ pmax) {
  const int cc = blockIdx.x, n = blockIdx.y;
  const int t = threadIdx.x;
  __shared__ float sx[CPB * HW_];      // 3136
  __shared__ float part_s[HW_][5];
  __shared__ float part_m[HW_][5];

  const float4* xv = (const float4*)(x + ((size_t)n * C_ + (size_t)cc * CPB) * HW_);
  for (int v = t; v < 784; v += 256) {
    float4 q = xv[v];
    sx[v * 4 + 0] = q.x; sx[v * 4 + 1] = q.y;
    sx[v * 4 + 2] = q.z; sx[v * 4 + 3] = q.w;
  }
  __syncthreads();

  if (t < 245) {
    int hw = t / 5, s = t % 5;
    float sm = 0.f, mx = -3.4e38f;
    #pragma unroll
    for (int j = 0; j < 13; ++j) {
      int c = s * 13 + j;
      if (c < CPB) {
        float a = sx[c * HW_ + hw];
        sm += a; mx = fmaxf(mx, a);
      }
    }
    part_s[hw][s] = sm; part_m[hw][s] = mx;
  }
  __syncthreads();

  if (t < HW_) {
    float sm = 0.f, mx = -3.4e38f;
    #pragma unroll
    for (int s = 0; s < 5; ++s) { sm += part_s[t][s]; mx = fmaxf(mx, part_m[t][s]); }
    size_t o = ((size_t)n * NCC + cc) * HW_ + t;
    psum[o] = sm; pmax[o] = mx;
  }
}

// ---------------- kernel 2: reduce chunks, compute g_hw gate per n ----------------
__global__ __launch_bounds__(64) void k_ghw(const float* __restrict__ psum,
                                            const float* __restrict__ pmax,
                                            const float* __restrict__ cw,
                                            const float* __restrict__ cb,
                                            const float* __restrict__ bnw,
                                            const float* __restrict__ bnb,
                                            const float* __restrict__ bnrm,
                                            const float* __restrict__ bnrv,
                                            float* __restrict__ ghw) {
  const int n = blockIdx.x;
  const int t = threadIdx.x;
  __shared__ float p2c[2][13][13];
  __shared__ float s_cw[98];

  for (int i = t; i < 2 * 13 * 13; i += 64) ((float*)p2c)[i] = 0.f;
  for (int i = t; i < 98; i += 64) s_cw[i] = cw[i];
  __syncthreads();

  if (t < HW_) {
    float sm = 0.f, mx = -3.4e38f;
    const float* ps = psum + (size_t)n * NCC * HW_ + t;
    const float* pm = pmax + (size_t)n * NCC * HW_ + t;
    for (int cc = 0; cc < NCC; ++cc) {
      sm += ps[cc * HW_];
      mx = fmaxf(mx, pm[cc * HW_]);
    }
    p2c[0][t / 7 + 3][t % 7 + 3] = sm * (1.f / C_);
    p2c[1][t / 7 + 3][t % 7 + 3] = mx;
  }
  __syncthreads();

  if (t < HW_) {
    int a = t / 7, b = t % 7;
    float y = cb[0];
    #pragma unroll
    for (int i2 = 0; i2 < 2; ++i2)
      #pragma unroll
      for (int p = 0; p < 7; ++p)
        #pragma unroll
        for (int q = 0; q < 7; ++q)
          y += p2c[i2][a + p][b + q] * s_cw[i2 * 49 + p * 7 + q];
    float sc = bnw[0] * rsqrtf(bnrv[0] + 1e-5f);
    y = (y - bnrm[0]) * sc + bnb[0];
    y = fmaxf(y, 0.f);
    ghw[n * HW_ + t] = 1.f / (1.f + __expf(-y));
  }
}

// ---------------- kernel 3: W/H pools, g_ch/g_cw gates, fused multiply ----------------
__global__ __launch_bounds__(256) void k_main(const float* __restrict__ x,
    const float* __restrict__ ghw,
    const float* __restrict__ cw, const float* __restrict__ cb,
    const float* __restrict__ bnw, const float* __restrict__ bnb,
    const float* __restrict__ bnrm, const float* __restrict__ bnrv,
    float* __restrict__ out) {
  const int cc = blockIdx.x, n = blockIdx.y;
  const int c0 = cc * CPB;
  const int t = threadIdx.x;

  __shared__ float sx[3431];       // 70 channels of 49 (+1 alignment gap at 147)
  __shared__ float pw[2][70][13];  // mean/max over W: [c][h+3], zero-padded h
  __shared__ float ph[2][70][13];  // mean/max over H: [c][w+3]
  __shared__ float s_cw[98];
  __shared__ float s_ghw[HW_];
  __shared__ float gch[CPB][7];
  __shared__ float gcw[CPB][7];

  for (int i = t; i < 98; i += 256) s_cw[i] = cw[i];
  for (int i = t; i < 2 * 70 * 13; i += 256) { ((float*)pw)[i] = 0.f; ((float*)ph)[i] = 0.f; }
  if (t < HW_) s_ghw[t] = ghw[n * HW_ + t];

  // main 64-channel chunk: float4 loads, elements land at sx[148 + e]
  const float4* xv = (const float4*)(x + ((size_t)n * C_ + c0) * HW_);
  for (int v = t; v < 784; v += 256) {
    float4 q = xv[v];
    int e = 148 + v * 4;
    sx[e + 0] = q.x; sx[e + 1] = q.y; sx[e + 2] = q.z; sx[e + 3] = q.w;
  }
  // halo channels: 3 low + 3 high, zero outside [0, C)
  for (int i = t; i < 2 * 3 * HW_; i += 256) {
    int side = i / 147, off = i % 147;
    int lc = side ? (67 + off / HW_) : (off / HW_);
    int c = c0 - 3 + lc;
    float vv = 0.f;
    if (c >= 0 && c < C_) vv = x[((size_t)n * C_ + c) * HW_ + off % HW_];
    sx[CHB(lc) + off % HW_] = vv;
  }
  __syncthreads();

  // pools over W (fixed h=k) and over H (fixed w=k) for all 70 local channels
  for (int i = t; i < 70 * 7; i += 256) {
    int cl = i / 7, k = i % 7;
    int base = CHB(cl);
    float s1 = 0.f, m1 = -3.4e38f, s2 = 0.f, m2 = -3.4e38f;
    #pragma unroll
    for (int j = 0; j < 7; ++j) {
      float a = sx[base + k * 7 + j];   // h=k, vary w
      s1 += a; m1 = fmaxf(m1, a);
      float b = sx[base + j * 7 + k];   // w=k, vary h
      s2 += b; m2 = fmaxf(m2, b);
    }
    pw[0][cl][k + 3] = s1 * (1.f / 7.f);
    pw[1][cl][k + 3] = m1;
    ph[0][cl][k + 3] = s2 * (1.f / 7.f);
    ph[1][cl][k + 3] = m2;
  }
  __syncthreads();

  // g_ch (conv over pw) and g_cw (conv over ph): 448 outputs each, shared weights
  {
    float cb0 = cb[0];
    float sc1 = bnw[1] * rsqrtf(bnrv[1] + 1e-5f);
    float sh1 = bnb[1], rm1 = bnrm[1];
    float sc2 = bnw[2] * rsqrtf(bnrv[2] + 1e-5f);
    float sh2 = bnb[2], rm2 = bnrm[2];
    for (int i = t; i < CPB * 7; i += 256) {
      int cl = i / 7, k = i % 7;   // output channel c0+cl, spatial index k
      float y1 = cb0, y2 = cb0;
      #pragma unroll
      for (int i2 = 0; i2 < 2; ++i2)
        #pragma unroll
        for (int p = 0; p < 7; ++p) {
          const float* r1 = &pw[i2][cl + p][k];  // rows cl..cl+6 == channels (c-3..c+3)
          const float* r2 = &ph[i2][cl + p][k];
          #pragma unroll
          for (int q = 0; q < 7; ++q) {
            float wv = s_cw[i2 * 49 + p * 7 + q];
            y1 += r1[q] * wv;
            y2 += r2[q] * wv;
          }
        }
      y1 = fmaxf((y1 - rm1) * sc1 + sh1, 0.f);
      y2 = fmaxf((y2 - rm2) * sc2 + sh2, 0.f);
      gch[cl][k] = 1.f / (1.f + __expf(-y1));
      gcw[cl][k] = 1.f / (1.f + __expf(-y2));
    }
  }
  __syncthreads();

  // fused multiply, float4 stores
  const float4* sxv = (const float4*)&sx[148];
  float4* outv = (float4*)(out + ((size_t)n * C_ + c0) * HW_);
  for (int v = t; v < 784; v += 256) {
    float4 q = sxv[v];
    float r[4] = {q.x, q.y, q.z, q.w};
    #pragma unroll
    for (int j = 0; j < 4; ++j) {
      int e = v * 4 + j;
      int cj = e / HW_, hw = e - cj * HW_;
      int h = hw / 7, w2 = hw - h * 7;
      float g = (s_ghw[hw] + gch[cj][h] + gcw[cj][w2]) * (1.f / 3.f);
      r[j] *= g;
    }
    float4 o; o.x = r[0]; o.y = r[1]; o.z = r[2]; o.w = r[3];
    outv[v] = o;
  }
}

extern "C" void kernel_launch(void* const* d_in, const int* in_sizes, int n_in,
                              void* d_out, int out_size, void* d_ws, size_t ws_size,
                              hipStream_t stream) {
  const float* x    = (const float*)d_in[0];
  const float* cw   = (const float*)d_in[1];
  const float* cb   = (const float*)d_in[2];
  const float* bnw  = (const float*)d_in[3];
  const float* bnb  = (const float*)d_in[4];
  const float* bnrm = (const float*)d_in[5];
  const float* bnrv = (const float*)d_in[6];
  float* out = (float*)d_out;

  float* psum = (float*)d_ws;                       // N*32*49
  float* pmax = psum + (size_t)N_ * NCC * HW_;      // N*32*49
  float* ghw  = pmax + (size_t)N_ * NCC * HW_;      // N*49

  k_poolc<<<dim3(NCC, N_), 256, 0, stream>>>(x, psum, pmax);
  k_ghw<<<dim3(N_), 64, 0, stream>>>(psum, pmax, cw, cb, bnw, bnb, bnrm, bnrv, ghw);
  k_main<<<dim3(NCC, N_), 256, 0, stream>>>(x, ghw, cw, cb, bnw, bnb, bnrm, bnrv, out);
}

// Round 3
// 101.426 us; speedup vs baseline: 1.4640x; 1.4640x over previous
//
#include <hip/hip_runtime.h>

#define N_ 256
#define C_ 2048
#define HW_ 49
#define CPB 64
#define NCC (C_/CPB)   // 32

typedef unsigned int u32;

// local-channel base in sx: 70 channels (3 halo low, 64 main, 3 halo high).
// Main chunk starts at 148 (16B-aligned for float4); halo-low at 0, gap at 147.
#define CHB(lc) ((lc) * HW_ + ((lc) >= 3 ? 1 : 0))

// ---------------- kernel 1: per-chunk channel-pool partials ----------------
__global__ __launch_bounds__(256) void k_poolc(const float* __restrict__ x,
                                               float* __restrict__ psum,
                                               float* __restrict__ pmax) {
  const int cc = blockIdx.x, n = blockIdx.y;
  const int t = threadIdx.x;
  __shared__ float sx[CPB * HW_];      // 3136
  __shared__ float part_s[HW_][5];
  __shared__ float part_m[HW_][5];

  const float4* xv = (const float4*)(x + ((size_t)n * C_ + (size_t)cc * CPB) * HW_);
  for (int v = t; v < 784; v += 256) {
    float4 q = xv[v];
    sx[v * 4 + 0] = q.x; sx[v * 4 + 1] = q.y;
    sx[v * 4 + 2] = q.z; sx[v * 4 + 3] = q.w;
  }
  __syncthreads();

  if (t < 245) {
    int hw = t / 5, s = t % 5;
    float sm = 0.f, mx = -3.4e38f;
    #pragma unroll
    for (int j = 0; j < 13; ++j) {
      int c = s * 13 + j;
      if (c < CPB) {
        float a = sx[c * HW_ + hw];
        sm += a; mx = fmaxf(mx, a);
      }
    }
    part_s[hw][s] = sm; part_m[hw][s] = mx;
  }
  __syncthreads();

  if (t < HW_) {
    float sm = 0.f, mx = -3.4e38f;
    #pragma unroll
    for (int s = 0; s < 5; ++s) { sm += part_s[t][s]; mx = fmaxf(mx, part_m[t][s]); }
    size_t o = ((size_t)n * NCC + cc) * HW_ + t;
    psum[o] = sm; pmax[o] = mx;
  }
}

// ---------------- kernel 2: reduce chunks, compute g_hw gate per n ----------------
__global__ __launch_bounds__(64) void k_ghw(const float* __restrict__ psum,
                                            const float* __restrict__ pmax,
                                            const float* __restrict__ cw,
                                            const float* __restrict__ cb,
                                            const float* __restrict__ bnw,
                                            const float* __restrict__ bnb,
                                            const float* __restrict__ bnrm,
                                            const float* __restrict__ bnrv,
                                            float* __restrict__ ghw) {
  const int n = blockIdx.x;
  const int t = threadIdx.x;
  __shared__ float p2c[2][13][13];
  __shared__ float s_cw[98];

  for (int i = t; i < 2 * 13 * 13; i += 64) ((float*)p2c)[i] = 0.f;
  for (int i = t; i < 98; i += 64) s_cw[i] = cw[i];
  __syncthreads();

  if (t < HW_) {
    float sm = 0.f, mx = -3.4e38f;
    const float* ps = psum + (size_t)n * NCC * HW_ + t;
    const float* pm = pmax + (size_t)n * NCC * HW_ + t;
    for (int cc = 0; cc < NCC; ++cc) {
      sm += ps[cc * HW_];
      mx = fmaxf(mx, pm[cc * HW_]);
    }
    p2c[0][t / 7 + 3][t % 7 + 3] = sm * (1.f / C_);
    p2c[1][t / 7 + 3][t % 7 + 3] = mx;
  }
  __syncthreads();

  if (t < HW_) {
    int a = t / 7, b = t % 7;
    float y = cb[0];
    #pragma unroll
    for (int i2 = 0; i2 < 2; ++i2)
      #pragma unroll
      for (int p = 0; p < 7; ++p)
        #pragma unroll
        for (int q = 0; q < 7; ++q)
          y += p2c[i2][a + p][b + q] * s_cw[i2 * 49 + p * 7 + q];
    float sc = bnw[0] * rsqrtf(bnrv[0] + 1e-5f);
    y = (y - bnrm[0]) * sc + bnb[0];
    y = fmaxf(y, 0.f);
    ghw[n * HW_ + t] = 1.f / (1.f + __expf(-y));
  }
}

// ---------------- kernel 3: W/H pools, g_ch/g_cw gates, fused multiply ----------------
__global__ __launch_bounds__(256) void k_main(const float* __restrict__ x,
    const float* __restrict__ ghw,
    const float* __restrict__ cw, const float* __restrict__ cb,
    const float* __restrict__ bnw, const float* __restrict__ bnb,
    const float* __restrict__ bnrm, const float* __restrict__ bnrv,
    float* __restrict__ out) {
  const int cc = blockIdx.x;
  const int n  = (N_ - 1) - blockIdx.y;   // reverse n: hit freshest L3 lines first
  const int c0 = cc * CPB;
  const int t  = threadIdx.x;

  __shared__ __align__(16) float sx[3432];            // 70ch x 49 (+gap at 147)
  __shared__ __align__(16) float pool[2][2][70][13];  // [conv][i2][lc][col], zero-padded cols
  __shared__ float s_cw[98];
  __shared__ float s_ghw[HW_];
  __shared__ float gch[CPB][7];
  __shared__ float gcw[CPB][7];

  // ---- hoisted scalar params (global loads in flight early) ----
  const int conv = t & 1, i2 = (t >> 1) & 1, cl = t >> 2;
  const int bi = 1 + conv;
  const float cb0 = cb[0];
  const float sc_bn = bnw[bi] * rsqrtf(bnrv[bi] + 1e-5f);
  const float rm_bn = bnrm[bi];
  const float sh_bn = bnb[bi];

  // ---- phase 0: stage ----
  for (int i = t; i < 98; i += 256) s_cw[i] = cw[i];
  if (t < HW_) s_ghw[t] = ghw[n * HW_ + t];
  {
    float4* pz = (float4*)&pool[0][0][0][0];  // 3640 floats = 910 float4
    float4 z = make_float4(0.f, 0.f, 0.f, 0.f);
    for (int i = t; i < 910; i += 256) pz[i] = z;
  }
  // halo channels first (scalar loads, long latency — get them in flight)
  for (int i = t; i < 2 * 3 * HW_; i += 256) {
    int side = i / 147, off = i % 147;
    int lc = side ? (67 + off / HW_) : (off / HW_);
    int c = c0 - 3 + lc;
    float vv = 0.f;
    if (c >= 0 && c < C_) vv = x[((size_t)n * C_ + c) * HW_ + off % HW_];
    sx[CHB(lc) + off % HW_] = vv;
  }
  const float4* xv = (const float4*)(x + ((size_t)n * C_ + c0) * HW_);
  float4* sxv = (float4*)&sx[148];
  for (int v = t; v < 784; v += 256) sxv[v] = xv[v];
  __syncthreads();

  // ---- phase 1: W-pools and H-pools for all 70 local channels ----
  for (int i = t; i < 70 * 7; i += 256) {
    int lc = i / 7, k = i % 7;
    int base = CHB(lc);
    float s1 = 0.f, m1 = -3.4e38f, s2 = 0.f, m2 = -3.4e38f;
    #pragma unroll
    for (int j = 0; j < 7; ++j) {
      float a = sx[base + k * 7 + j];   // h=k, vary w  -> W-reduction
      s1 += a; m1 = fmaxf(m1, a);
      float b = sx[base + j * 7 + k];   // w=k, vary h  -> H-reduction
      s2 += b; m2 = fmaxf(m2, b);
    }
    pool[0][0][lc][k + 3] = s1 * (1.f / 7.f);  // g_ch conv input: mean over W
    pool[0][1][lc][k + 3] = m1;                //                  max  over W
    pool[1][0][lc][k + 3] = s2 * (1.f / 7.f);  // g_cw conv input: mean over H
    pool[1][1][lc][k + 3] = m2;                //                  max  over H
  }
  __syncthreads();

  // ---- phase 2: conv via register rows. thread = (conv, i2, cl) ----
  {
    const float* Pb = &pool[conv][i2][cl][0];   // rows cl..cl+6, 13 cols each
    const float* Wb = &s_cw[i2 * 49];
    float acc[7] = {0.f, 0.f, 0.f, 0.f, 0.f, 0.f, 0.f};
    #pragma unroll
    for (int p = 0; p < 7; ++p) {
      float row[13];
      #pragma unroll
      for (int c = 0; c < 13; ++c) row[c] = Pb[p * 13 + c];  // 13 indep LDS reads
      #pragma unroll
      for (int q = 0; q < 7; ++q) {
        float wv = Wb[p * 7 + q];
        #pragma unroll
        for (int k = 0; k < 7; ++k) acc[k] += row[k + q] * wv;  // reg-only FMAs
      }
    }
    // sum the i2=0 / i2=1 partials: partner lane = lane ^ 2 (i2 is bit 1 of t)
    float fsum[7];
    #pragma unroll
    for (int k = 0; k < 7; ++k) fsum[k] = acc[k] + __shfl_xor(acc[k], 2, 64);
    if (i2 == 0) {
      float* gp = conv ? &gcw[cl][0] : &gch[cl][0];
      #pragma unroll
      for (int k = 0; k < 7; ++k) {
        float y = (fsum[k] + cb0 - rm_bn) * sc_bn + sh_bn;
        y = fmaxf(y, 0.f);
        gp[k] = 1.f / (1.f + __expf(-y));
      }
    }
  }
  __syncthreads();

  // ---- phase 3: fused multiply, float4 I/O ----
  float4* outv = (float4*)(out + ((size_t)n * C_ + c0) * HW_);
  for (int v = t; v < 784; v += 256) {
    float4 q = sxv[v];
    int e0 = v * 4;
    int cj = e0 / 49;            // one magic-div per float4
    int hw0 = e0 - cj * 49;
    float r[4] = {q.x, q.y, q.z, q.w};
    #pragma unroll
    for (int j = 0; j < 4; ++j) {
      int hw = hw0 + j;
      int cjj = cj + (hw >= 49);
      hw -= (hw >= 49) ? 49 : 0;
      int h = (hw * 37) >> 8;    // floor(hw/7) for hw<=51
      int w2 = hw - h * 7;
      float g = (s_ghw[hw] + gch[cjj][h] + gcw[cjj][w2]) * (1.f / 3.f);
      r[j] *= g;
    }
    outv[v] = make_float4(r[0], r[1], r[2], r[3]);
  }
}

extern "C" void kernel_launch(void* const* d_in, const int* in_sizes, int n_in,
                              void* d_out, int out_size, void* d_ws, size_t ws_size,
                              hipStream_t stream) {
  const float* x    = (const float*)d_in[0];
  const float* cw   = (const float*)d_in[1];
  const float* cb   = (const float*)d_in[2];
  const float* bnw  = (const float*)d_in[3];
  const float* bnb  = (const float*)d_in[4];
  const float* bnrm = (const float*)d_in[5];
  const float* bnrv = (const float*)d_in[6];
  float* out = (float*)d_out;

  float* psum = (float*)d_ws;                       // N*32*49
  float* pmax = psum + (size_t)N_ * NCC * HW_;      // N*32*49
  float* ghw  = pmax + (size_t)N_ * NCC * HW_;      // N*49

  k_poolc<<<dim3(NCC, N_), 256, 0, stream>>>(x, psum, pmax);
  k_ghw<<<dim3(N_), 64, 0, stream>>>(psum, pmax, cw, cb, bnw, bnb, bnrm, bnrv, ghw);
  k_main<<<dim3(NCC, N_), 256, 0, stream>>>(x, ghw, cw, cb, bnw, bnb, bnrm, bnrv, out);
}

// Round 4
// 86.616 us; speedup vs baseline: 1.7144x; 1.1710x over previous
//
#include <hip/hip_runtime.h>

#define N_ 256
#define C_ 2048
#define HW_ 49
#define CPB 64
#define NCC (C_/CPB)   // 32

// local-channel base in sx: 70 channels (3 halo low, 64 main, 3 halo high).
// Main chunk starts at 148 (16B-aligned for float4); halo-low at 0, gap at 147.
#define CHB(lc) ((lc) * HW_ + ((lc) >= 3 ? 1 : 0))

// ---------------- kernel 1: per-chunk channel-pool partials ----------------
__global__ __launch_bounds__(256) void k_poolc(const float* __restrict__ x,
                                               float* __restrict__ psum,
                                               float* __restrict__ pmax) {
  const int cc = blockIdx.x, n = blockIdx.y;
  const int t = threadIdx.x;
  __shared__ float sx[CPB * HW_];      // 3136
  __shared__ float part_s[HW_][5];
  __shared__ float part_m[HW_][5];

  const float4* xv = (const float4*)(x + ((size_t)n * C_ + (size_t)cc * CPB) * HW_);
  for (int v = t; v < 784; v += 256) {
    float4 q = xv[v];
    sx[v * 4 + 0] = q.x; sx[v * 4 + 1] = q.y;
    sx[v * 4 + 2] = q.z; sx[v * 4 + 3] = q.w;
  }
  __syncthreads();

  if (t < 245) {
    int hw = t / 5, s = t % 5;
    float sm = 0.f, mx = -3.4e38f;
    #pragma unroll
    for (int j = 0; j < 13; ++j) {
      int c = s * 13 + j;
      if (c < CPB) {
        float a = sx[c * HW_ + hw];
        sm += a; mx = fmaxf(mx, a);
      }
    }
    part_s[hw][s] = sm; part_m[hw][s] = mx;
  }
  __syncthreads();

  if (t < HW_) {
    float sm = 0.f, mx = -3.4e38f;
    #pragma unroll
    for (int s = 0; s < 5; ++s) { sm += part_s[t][s]; mx = fmaxf(mx, part_m[t][s]); }
    size_t o = ((size_t)n * NCC + cc) * HW_ + t;
    psum[o] = sm; pmax[o] = mx;
  }
}

// ---------------- kernel 2: reduce chunks, compute g_hw gate per n ----------------
__global__ __launch_bounds__(64) void k_ghw(const float* __restrict__ psum,
                                            const float* __restrict__ pmax,
                                            const float* __restrict__ cw,
                                            const float* __restrict__ cb,
                                            const float* __restrict__ bnw,
                                            const float* __restrict__ bnb,
                                            const float* __restrict__ bnrm,
                                            const float* __restrict__ bnrv,
                                            float* __restrict__ ghw) {
  const int n = blockIdx.x;
  const int t = threadIdx.x;
  __shared__ float p2c[2][13][13];
  __shared__ float s_cw[98];

  for (int i = t; i < 2 * 13 * 13; i += 64) ((float*)p2c)[i] = 0.f;
  for (int i = t; i < 98; i += 64) s_cw[i] = cw[i];
  __syncthreads();

  if (t < HW_) {
    float sm = 0.f, mx = -3.4e38f;
    const float* ps = psum + (size_t)n * NCC * HW_ + t;
    const float* pm = pmax + (size_t)n * NCC * HW_ + t;
    for (int cc = 0; cc < NCC; ++cc) {
      sm += ps[cc * HW_];
      mx = fmaxf(mx, pm[cc * HW_]);
    }
    p2c[0][t / 7 + 3][t % 7 + 3] = sm * (1.f / C_);
    p2c[1][t / 7 + 3][t % 7 + 3] = mx;
  }
  __syncthreads();

  if (t < HW_) {
    int a = t / 7, b = t % 7;
    float y = cb[0];
    #pragma unroll
    for (int i2 = 0; i2 < 2; ++i2)
      #pragma unroll
      for (int p = 0; p < 7; ++p)
        #pragma unroll
        for (int q = 0; q < 7; ++q)
          y += p2c[i2][a + p][b + q] * s_cw[i2 * 49 + p * 7 + q];
    float sc = bnw[0] * rsqrtf(bnrv[0] + 1e-5f);
    y = (y - bnrm[0]) * sc + bnb[0];
    y = fmaxf(y, 0.f);
    ghw[n * HW_ + t] = 1.f / (1.f + __expf(-y));
  }
}

// ---------------- kernel 3: W/H pools, g_ch/g_cw gates, fused multiply ----------------
// LDS map (floats):  [0..3431]   sx       (live: stage..phase1)
//                    [0..447]    gch[64][7]  (alias on sx; live: phase2..phase3)
//                    [448..895]  gcw[64][7]  (alias on sx)
//                    [3432..5671] pool[2][2][70][8]  (32B rows, b128-readable)
//                    [5672..5769] s_cw[98]
//                    [5770..5818] s_ghw[49]
__global__ __launch_bounds__(256, 6) void k_main(const float* __restrict__ x,
    const float* __restrict__ ghw,
    const float* __restrict__ cw, const float* __restrict__ cb,
    const float* __restrict__ bnw, const float* __restrict__ bnb,
    const float* __restrict__ bnrm, const float* __restrict__ bnrv,
    float* __restrict__ out) {
  const int cc = blockIdx.x;
  const int n  = (N_ - 1) - blockIdx.y;
  const int c0 = cc * CPB;
  const int t  = threadIdx.x;

  __shared__ __align__(16) float smem[5819];
  float* sx    = smem;
  float* gch   = smem;          // alias (sx dead after phase 1)
  float* gcw   = smem + 448;    // alias
  float* pool  = smem + 3432;   // [2][2][70][8]
  float* s_cw  = smem + 5672;
  float* s_ghw = smem + 5770;

  const int conv = t & 1, i2 = (t >> 1) & 1, cl = t >> 2;
  const int bi = 1 + conv;
  const float cb0 = cb[0];
  const float sc_bn = bnw[bi] * rsqrtf(bnrv[bi] + 1e-5f);
  const float rm_bn = bnrm[bi];
  const float sh_bn = bnb[bi];

  // ---- phase 0: stage ----
  for (int i = t; i < 98; i += 256) s_cw[i] = cw[i];
  if (t < HW_) s_ghw[t] = ghw[n * HW_ + t];
  // halo channels (scalar, long latency — issue early)
  for (int i = t; i < 2 * 3 * HW_; i += 256) {
    int side = i / 147, off = i % 147;
    int lc = side ? (67 + off / HW_) : (off / HW_);
    int c = c0 - 3 + lc;
    float vv = 0.f;
    if (c >= 0 && c < C_) vv = x[((size_t)n * C_ + c) * HW_ + off % HW_];
    sx[CHB(lc) + off % HW_] = vv;
  }
  // main chunk: float4 loads held in REGISTERS + mirrored to LDS for pooling
  const float4* xv = (const float4*)(x + ((size_t)n * C_ + c0) * HW_);
  float4* sxv = (float4*)(sx + 148);
  float4 xr[4];
  #pragma unroll
  for (int i = 0; i < 4; ++i) {
    int v = t + i * 256;
    if (v < 784) { xr[i] = xv[v]; sxv[v] = xr[i]; }
  }
  __syncthreads();

  // ---- phase 1: W-pools / H-pools for all 70 local channels ----
  for (int i = t; i < 70 * 7; i += 256) {
    int lc = i / 7, k = i % 7;
    int base = CHB(lc);
    float s1 = 0.f, m1 = -3.4e38f, s2 = 0.f, m2 = -3.4e38f;
    #pragma unroll
    for (int j = 0; j < 7; ++j) {
      float a = sx[base + k * 7 + j];   // h=k, vary w  -> W-reduction (g_ch input)
      s1 += a; m1 = fmaxf(m1, a);
      float b = sx[base + j * 7 + k];   // w=k, vary h  -> H-reduction (g_cw input)
      s2 += b; m2 = fmaxf(m2, b);
    }
    pool[((0 * 2 + 0) * 70 + lc) * 8 + k] = s1 * (1.f / 7.f);
    pool[((0 * 2 + 1) * 70 + lc) * 8 + k] = m1;
    pool[((1 * 2 + 0) * 70 + lc) * 8 + k] = s2 * (1.f / 7.f);
    pool[((1 * 2 + 1) * 70 + lc) * 8 + k] = m2;
  }
  __syncthreads();

  // ---- phase 2: conv via b128 register rows; thread = (conv, i2, cl) ----
  {
    const float* Wb = s_cw + i2 * 49;
    const float* Pb = pool + ((conv * 2 + i2) * 70 + cl) * 8;
    float acc[7] = {0.f, 0.f, 0.f, 0.f, 0.f, 0.f, 0.f};
    #pragma unroll
    for (int p = 0; p < 7; ++p) {
      float4 r0 = *(const float4*)(Pb + p * 8);
      float4 r1 = *(const float4*)(Pb + p * 8 + 4);
      float row[7] = {r0.x, r0.y, r0.z, r0.w, r1.x, r1.y, r1.z};
      #pragma unroll
      for (int q = 0; q < 7; ++q) {
        float wv = Wb[p * 7 + q];
        #pragma unroll
        for (int k = 0; k < 7; ++k) {
          int c = k + q - 3;                 // spatial zero-pad via static bounds
          if (c >= 0 && c < 7) acc[k] += row[c] * wv;
        }
      }
    }
    float fsum[7];
    #pragma unroll
    for (int k = 0; k < 7; ++k) fsum[k] = acc[k] + __shfl_xor(acc[k], 2, 64);
    if (i2 == 0) {
      float* gp = (conv ? gcw : gch) + cl * 7;
      #pragma unroll
      for (int k = 0; k < 7; ++k) {
        float y = (fsum[k] + cb0 - rm_bn) * sc_bn + sh_bn;
        y = fmaxf(y, 0.f);
        gp[k] = 1.f / (1.f + __expf(-y));
      }
    }
  }
  __syncthreads();

  // ---- phase 3: fused multiply from registers, float4 stores ----
  float4* outv = (float4*)(out + ((size_t)n * C_ + c0) * HW_);
  #pragma unroll
  for (int i = 0; i < 4; ++i) {
    int v = t + i * 256;
    if (v >= 784) break;
    float4 q = xr[i];
    int e0 = v * 4;
    int cj = e0 / 49;
    int hw0 = e0 - cj * 49;
    float r[4] = {q.x, q.y, q.z, q.w};
    #pragma unroll
    for (int j = 0; j < 4; ++j) {
      int hw = hw0 + j;
      int cjj = cj + (hw >= 49);
      hw -= (hw >= 49) ? 49 : 0;
      int h = (hw * 37) >> 8;    // floor(hw/7) for hw<=51
      int w2 = hw - h * 7;
      float g = (s_ghw[hw] + gch[cjj * 7 + h] + gcw[cjj * 7 + w2]) * (1.f / 3.f);
      r[j] *= g;
    }
    outv[v] = make_float4(r[0], r[1], r[2], r[3]);
  }
}

extern "C" void kernel_launch(void* const* d_in, const int* in_sizes, int n_in,
                              void* d_out, int out_size, void* d_ws, size_t ws_size,
                              hipStream_t stream) {
  const float* x    = (const float*)d_in[0];
  const float* cw   = (const float*)d_in[1];
  const float* cb   = (const float*)d_in[2];
  const float* bnw  = (const float*)d_in[3];
  const float* bnb  = (const float*)d_in[4];
  const float* bnrm = (const float*)d_in[5];
  const float* bnrv = (const float*)d_in[6];
  float* out = (float*)d_out;

  float* psum = (float*)d_ws;                       // N*32*49
  float* pmax = psum + (size_t)N_ * NCC * HW_;      // N*32*49
  float* ghw  = pmax + (size_t)N_ * NCC * HW_;      // N*49

  k_poolc<<<dim3(NCC, N_), 256, 0, stream>>>(x, psum, pmax);
  k_ghw<<<dim3(N_), 64, 0, stream>>>(psum, pmax, cw, cb, bnw, bnb, bnrm, bnrv, ghw);
  k_main<<<dim3(NCC, N_), 256, 0, stream>>>(x, ghw, cw, cb, bnw, bnb, bnrm, bnrv, out);
}